// Round 18
// baseline (226.432 us; speedup 1.0000x reference)
//
#include <hip/hip_runtime.h>

typedef short s8v __attribute__((ext_vector_type(8)));   // 8 bf16
typedef short s4v __attribute__((ext_vector_type(4)));   // 4 bf16
typedef float f4v __attribute__((ext_vector_type(4)));
typedef float f16v __attribute__((ext_vector_type(16)));
typedef unsigned u32v2 __attribute__((ext_vector_type(2)));
typedef unsigned u32v4 __attribute__((ext_vector_type(4)));
typedef unsigned short u16;

#define MFMA(a,b,c)   __builtin_amdgcn_mfma_f32_16x16x32_bf16(a,b,c,0,0,0)
#define MFMA32(a,b,c) __builtin_amdgcn_mfma_f32_32x32x16_bf16(a,b,c,0,0,0)

__device__ __forceinline__ float bf2f(u16 x){
  unsigned u = ((unsigned)x) << 16;
  return __builtin_bit_cast(float, u);
}
__device__ __forceinline__ u16 f2bf(float f){
  unsigned u = __builtin_bit_cast(unsigned, f);
  u += 0x7FFFu + ((u >> 16) & 1u);           // RNE
  return (u16)(u >> 16);
}
// packed bf16 convert: D.lo = bf16(lo), D.hi = bf16(hi)
__device__ __forceinline__ unsigned cvtpk(float lo, float hi){
  unsigned r;
  asm("v_cvt_pk_bf16_f32 %0, %1, %2" : "=v"(r) : "v"(lo), "v"(hi));
  return r;
}
// cross-half exchange
__device__ __forceinline__ void plswap(unsigned &x, unsigned &y){
  asm volatile("v_permlane32_swap_b32 %0, %1" : "+v"(x), "+v"(y));
}

__device__ __forceinline__ void gload16(const void* g, void* l){
  __builtin_amdgcn_global_load_lds((const __attribute__((address_space(1))) unsigned*)g,
                                   (__attribute__((address_space(3))) unsigned*)l, 16, 0, 0);
}
__device__ __forceinline__ void nt_store4(float* p, f4v v){
  __builtin_nontemporal_store(v, (f4v*)p);
}

// ---------------- problem constants ----------------
#define CC   256
#define CK   128
#define HW   2304
#define NF   12          // B*N frames
// exp2 constant: 128^-0.5 * log2(e)
#define C2E  0.1275174996992022f
// ws byte offsets (kT | v | ctx48 | rs48 | params | weights)
#define OFF_KT   0u
#define OFF_V    7077888u
#define OFF_CTX  14155776u
#define OFF_RS   42467328u
#define OFF_PAR  42909696u
#define OFF_WK16 42911744u
#define OFF_WV16 42977280u
#define OFF_WF16 43042816u
#define OFF_WCMB 43304960u

// ---------------- K0: weight converts + params (BN fold, Wcomb = WfR*Wo, btot) ----------------
__global__ void k0_params(const float* __restrict__ Wkf, const float* __restrict__ Wvf,
                          const float* __restrict__ bk, const float* __restrict__ gk,
                          const float* __restrict__ betak, const float* __restrict__ mk,
                          const float* __restrict__ vk, const float* __restrict__ Wo,
                          const float* __restrict__ Wf, const float* __restrict__ bo,
                          const float* __restrict__ bfv,
                          u16* __restrict__ Wk16, u16* __restrict__ Wv16, u16* __restrict__ Wf16,
                          float* kscale, float* kbias, float* btot, u16* Wcomb){
  int c = blockIdx.x;      // 0..127
  int o = threadIdx.x;     // 0..255
  int gid = c*256 + o;     // 0..32767
  Wk16[gid] = f2bf(Wkf[gid]);
  Wv16[gid] = f2bf(Wvf[gid]);
  {
    f4v wf4 = *(const f4v*)(Wf + (size_t)gid*4);
    #pragma unroll
    for(int u=0;u<4;u++) Wf16[(size_t)gid*4+u] = f2bf(wf4[u]);
  }
  float acc = 0.f;
  for(int m=0;m<256;m++)
    acc += Wf[(size_t)o*512 + 256 + m] * Wo[(size_t)m*128 + c];
  Wcomb[(size_t)o*128 + c] = f2bf(acc);
  if (c == 0){
    float a2 = 0.f;
    for(int m=0;m<256;m++)
      a2 += Wf[(size_t)o*512 + 256 + m] * bo[m];
    btot[o] = bfv[o] + 2.0f*a2;
    if (o < 128){
      float inv = gk[o] * rsqrtf(vk[o] + 1e-5f);
      kscale[o] = inv;
      kbias[o]  = betak[o] + (bk[o] - mk[o])*inv;
    }
  }
}

// ---- shared helper: stage x[c][pb+0..63] fp32 -> LDS bf16 tile, rows p (512 B, XOR-swizzled) ----
__device__ __forceinline__ void stage_xt(const float* __restrict__ xf, int pb, int tid, char* xt){
  #pragma unroll
  for(int it=0; it<8; ++it){
    int idx = tid + 256*it;          // 0..2047: cp = c/2 (0..127), slot (0..15)
    int cp = idx>>4, slot = idx&15;
    const float* s0 = xf + (size_t)(2*cp  )*HW + pb + slot*4;
    const float* s1 = xf + (size_t)(2*cp+1)*HW + pb + slot*4;
    f4v va = *(const f4v*)s0;
    f4v vb = *(const f4v*)s1;
    #pragma unroll
    for(int u=0;u<4;u++){
      int p = slot*4+u;
      *(unsigned*)(xt + p*512 + ((4*cp) ^ ((p&7)<<4))) = cvtpk(va[u], vb[u]);
    }
  }
}
__device__ __forceinline__ s8v xt_frag(const char* xt, int r, int kt, int g){
  return *(const s8v*)(xt + r*512 + (((unsigned)(64*kt+16*g)) ^ ((unsigned)(r&7)<<4)));
}

// ---------------- K1: kT = BN(x^T*Wk^T) (stored [q][o]), v = Wv*x (stored [o][p]) ----------------
__global__ __launch_bounds__(256) void k1_kv(const float* __restrict__ x, const u16* __restrict__ Wk,
                                             const u16* __restrict__ Wv, const float* __restrict__ bv,
                                             const float* __restrict__ kscale, const float* __restrict__ kbias,
                                             u16* __restrict__ kT, u16* __restrict__ vout){
  int f  = blockIdx.y;
  int pb = blockIdx.x*64;
  int tid = threadIdx.x;
  int w = tid>>6, l = tid&63, s = l&15, g = l>>4;
  __shared__ char xt[32768];
  stage_xt(x + (size_t)f*CC*HW, pb, tid, xt);
  __syncthreads();
  { // k path
    s8v afr[8];
    #pragma unroll
    for(int kt=0;kt<8;kt++) afr[kt] = xt_frag(xt, 16*w+s, kt, g);
    f4v acc[8] = {};
    #pragma unroll
    for(int kt=0;kt<8;kt++){
      #pragma unroll
      for(int nt=0;nt<8;nt++){
        s8v b = *(const s8v*)(Wk + (size_t)(16*nt+s)*CC + 32*kt + 8*g);
        acc[nt] = MFMA(afr[kt], b, acc[nt]);
      }
    }
    u16* kout = kT + (size_t)f*HW*CK;
    int q0 = pb + 16*w;
    #pragma unroll
    for(int nt=0;nt<8;nt++){
      int o = 16*nt + s;
      float sc = kscale[o], bi = kbias[o];
      #pragma unroll
      for(int r=0;r<4;r++){
        int q = q0 + 4*g + r;
        kout[(size_t)q*CK + o] = f2bf(acc[nt][r]*sc + bi);
      }
    }
  }
  { // v path
    s8v afr[2][8];
    #pragma unroll
    for(int mt=0;mt<2;mt++)
      #pragma unroll
      for(int kt=0;kt<8;kt++)
        afr[mt][kt] = *(const s8v*)(Wv + (size_t)(32*w+16*mt+s)*CC + 32*kt + 8*g);
    f4v acc[2][4] = {};
    #pragma unroll
    for(int kt=0;kt<8;kt++){
      #pragma unroll
      for(int nt=0;nt<4;nt++){
        s8v b = xt_frag(xt, 16*nt+s, kt, g);
        #pragma unroll
        for(int mt=0;mt<2;mt++)
          acc[mt][nt] = MFMA(afr[mt][kt], b, acc[mt][nt]);
      }
    }
    u16* vf = vout + (size_t)f*CK*HW;
    #pragma unroll
    for(int mt=0;mt<2;mt++){
      #pragma unroll
      for(int r=0;r<4;r++){
        int o = 32*w + 16*mt + 4*g + r;
        float bvo = bv[o];
        #pragma unroll
        for(int nt=0;nt<4;nt++)
          vf[(size_t)o*HW + pb + 16*nt + s] = f2bf(acc[mt][nt][r] + bvo);
      }
    }
  }
}

// ---------------- K2: attention core, 32x32 MFMA + in-register P.
//  K double-buffered (2x16K), V SINGLE-buffered (16K) -> 48 KB -> 3 blocks/CU.
//  3-barrier counted-wait pipeline: B1 vmcnt(V ready) | PV | B2 lgkm(reads done) | STAGE_V | B3 vmcnt(K ready).
//  Writes UNNORMALIZED partial ctx (48 planes) + partial rowsums; k2c/k3 combine. ----------------
__global__ __launch_bounds__(256, 3) void k2_attn(const u16* __restrict__ kT, const u16* __restrict__ v,
                                                  u16* __restrict__ ctxS, float* __restrict__ rs){
  int qb  = blockIdx.x;          // 0..17 (128 q rows each)
  int yy  = blockIdx.y;          // 0..47 = bij*2 + half
  int bij = yy>>1, half = yy&1;
  int b = bij/6, r6_ = bij - 6*b, i = r6_>>1, jj = r6_&1;
  int adj0 = (i==0) ? 1 : 0;
  int adj1 = (i==2) ? 1 : 2;
  int j = jj ? adj1 : adj0;
  int tid = threadIdx.x;
  int w = tid>>6, l = tid&63;
  int lq = l&31, hh = l>>5;      // q-col within wave block, half
  int q0 = qb*128 + w*32;        // wave covers q0..q0+31

  __shared__ char L[49152];      // K dbuf 2x16K | V single 16K

  const u16* kTi = kT + (size_t)(b*3+i)*HW*CK;
  const u16* kTj = kT + (size_t)(b*3+j)*HW*CK;
  const u16* vj  = v  + (size_t)(b*3+j)*CK*HW;

  // Q B-frags: col=q=lq, k = c = 16*st + 8*hh + jv
  s8v qfr[8];
  #pragma unroll
  for(int st=0; st<8; ++st)
    qfr[st] = *(const s8v*)(kTi + (size_t)(q0+lq)*CK + 16*st + 8*hh);

  f16v ctx[4] = {};              // 4 c-blocks, D[c][q]
  float psum = 0.f;

  auto STAGE_K = [&](int p0, int buf){
    const char* kbase = (const char*)kTj + (size_t)p0*256;
    char* lK = L + buf*16384 + w*1024;
    #pragma unroll
    for(int it=0; it<4; ++it){
      unsigned Lo = (unsigned)tid*16u + (unsigned)it*4096u;
      unsigned Gs = Lo ^ (((Lo>>8)&7u)<<4);               // K: 256 B rows
      gload16(kbase + Gs, lK + it*4096);
    }
  };
  auto STAGE_V = [&](int p0){
    const char* vbase = (const char*)vj + (size_t)p0*2;
    char* lV = L + 32768 + w*1024;
    #pragma unroll
    for(int it=0; it<4; ++it){
      unsigned Lo = (unsigned)tid*16u + (unsigned)it*4096u;
      unsigned row = Lo>>7;                               // V: 128 B rows
      unsigned col = (Lo & 127u) ^ ((row&7u)<<4);
      gload16(vbase + (size_t)row*(HW*2) + col, lV + it*4096);
    }
  };

  int pbase = half*18;
  STAGE_K(pbase*64, 0);
  STAGE_V(pbase*64);
  __syncthreads();               // drains vmcnt(0): K(0), V(0) ready
  int kcur = 0;

  for(int pt=0; pt<18; ++pt){
    int p0 = (pbase + pt)*64;
    if (pt < 17) STAGE_K(p0+64, kcur^1);   // issue next K tile (4 DMAs)
    const char* lK = L + kcur*16384;
    const char* lV = L + 32768;

    // ---- QK^T swapped 32x32: sa[pb] = S^T tile, row=p (16/lane), col=q=lq ----
    f16v sa[2] = {};
    #pragma unroll
    for(int st=0; st<8; ++st){
      #pragma unroll
      for(int pb=0; pb<2; ++pb){
        unsigned row = (unsigned)(32*pb + lq);
        unsigned cb_ = ((unsigned)(32*st + 16*hh)) ^ ((row&7u)<<4);
        s8v kfr = *(const s8v*)(lK + row*256 + cb_);
        sa[pb] = MFMA32(kfr, qfr[st], sa[pb]);
      }
    }
    // ---- softmax fully in-register (both pb) -> P frags ----
    s8v pf[2][2];
    #pragma unroll
    for(int pb=0; pb<2; ++pb){
      float e0 = exp2f(sa[pb][0]*C2E),  e1 = exp2f(sa[pb][1]*C2E);
      float e2 = exp2f(sa[pb][2]*C2E),  e3 = exp2f(sa[pb][3]*C2E);
      float e4 = exp2f(sa[pb][4]*C2E),  e5 = exp2f(sa[pb][5]*C2E);
      float e6 = exp2f(sa[pb][6]*C2E),  e7 = exp2f(sa[pb][7]*C2E);
      float e8 = exp2f(sa[pb][8]*C2E),  e9 = exp2f(sa[pb][9]*C2E);
      float ea = exp2f(sa[pb][10]*C2E), eb = exp2f(sa[pb][11]*C2E);
      float ec = exp2f(sa[pb][12]*C2E), ed = exp2f(sa[pb][13]*C2E);
      float ee = exp2f(sa[pb][14]*C2E), ef = exp2f(sa[pb][15]*C2E);
      psum += ((e0+e1)+(e2+e3)) + ((e4+e5)+(e6+e7)) +
              ((e8+e9)+(ea+eb)) + ((ec+ed)+(ee+ef));
      unsigned c0 = cvtpk(e0,e1), c1 = cvtpk(e2,e3), c2 = cvtpk(e4,e5), c3 = cvtpk(e6,e7);
      unsigned c4 = cvtpk(e8,e9), c5 = cvtpk(ea,eb), c6 = cvtpk(ec,ed), c7 = cvtpk(ee,ef);
      plswap(c0, c2); plswap(c1, c3);       // octet p' 0..15
      plswap(c4, c6); plswap(c5, c7);       // octet p' 16..31
      u32v4 w0 = {c0, c1, c2, c3};
      u32v4 w1 = {c4, c5, c6, c7};
      pf[pb][0] = __builtin_bit_cast(s8v, w0);
      pf[pb][1] = __builtin_bit_cast(s8v, w1);
    }
    // ---- B1: V(pt) landed everywhere. Outstanding (own): V(pt) [4, oldest] then K(pt+1) [4]. ----
    if (pt < 17) asm volatile("s_waitcnt vmcnt(4)" ::: "memory");
    else         asm volatile("s_waitcnt vmcnt(0)" ::: "memory");
    __builtin_amdgcn_s_barrier();
    __builtin_amdgcn_sched_barrier(0);
    // ---- PV: ctx[c][q] += V[c][p] * P[q][p], V from single buffer ----
    #pragma unroll
    for(int pb=0; pb<2; ++pb){
      #pragma unroll
      for(int cb=0; cb<4; ++cb){
        unsigned row = (unsigned)(32*cb + lq);
        unsigned swz = (row&7u)<<4;
        unsigned off0 = ((unsigned)(64*pb      + 16*hh)) ^ swz;
        unsigned off1 = ((unsigned)(64*pb + 32 + 16*hh)) ^ swz;
        s8v vf0 = *(const s8v*)(lV + row*128 + off0);
        s8v vf1 = *(const s8v*)(lV + row*128 + off1);
        ctx[cb] = MFMA32(vf0, pf[pb][0], ctx[cb]);
        ctx[cb] = MFMA32(vf1, pf[pb][1], ctx[cb]);
      }
    }
    // ---- B2: all waves' LDS reads (K and V) retired -> safe to overwrite V and old K ----
    asm volatile("s_waitcnt lgkmcnt(0)" ::: "memory");
    __builtin_amdgcn_s_barrier();
    __builtin_amdgcn_sched_barrier(0);
    if (pt < 17){
      STAGE_V(p0+64);                       // 4 DMAs into the single V buffer
      // ---- B3: K(pt+1) landed. Outstanding: K(pt+1) [4, oldest] then V(pt+1) [4]. ----
      asm volatile("s_waitcnt vmcnt(4)" ::: "memory");
      __builtin_amdgcn_s_barrier();
      __builtin_amdgcn_sched_barrier(0);
    }
    kcur ^= 1;
  }

  // ---- rowsum: lane pair (lq, lq+32) both hold partial sums for q = q0+lq ----
  float xsum = psum + __shfl_xor(psum, 32);
  if (l < 32)
    rs[(size_t)yy*HW + q0 + lq] = xsum;

  // ---- write UNNORMALIZED partial ctx plane [yy][q][c]; c = 32cb + 8qd + 4hh + 0..3 ----
  u16* cS = ctxS + (size_t)yy*HW*CK;
  #pragma unroll
  for(int cb=0; cb<4; ++cb){
    #pragma unroll
    for(int qd=0; qd<4; ++qd){
      u32v2 pk;
      pk[0] = cvtpk(ctx[cb][4*qd+0], ctx[cb][4*qd+1]);
      pk[1] = cvtpk(ctx[cb][4*qd+2], ctx[cb][4*qd+3]);
      *(u32v2*)(cS + (size_t)(q0+lq)*CK + 32*cb + 8*qd + 4*hh) = pk;
    }
  }
}

// ---------------- K2c: recompute QK^T for i==0 planes, write NORMALIZED fp32 attn (NT stores) ----------------
__global__ __launch_bounds__(256) void k2c_attnmap(const u16* __restrict__ kT,
                                                   const float* __restrict__ rs,
                                                   float* __restrict__ attn_out){
  int qb = blockIdx.x;           // 0..35
  int y  = blockIdx.y;           // 0..15: plane = y>>1, ph = y&1
  int plane = y>>1, ph = y&1;
  int b = plane>>1, jj = plane&1, j = jj + 1;   // i==0: adj frames are 1,2
  int tid = threadIdx.x;
  int w = tid>>6, l = tid&63, s = l&15, g = l>>4;
  int q0 = qb*64 + w*16;

  __shared__ char  ldsK[16384];
  __shared__ float ptile[4][16][68];
  __shared__ float inv16[4][16];

  const u16* kTi = kT + (size_t)(b*3)*HW*CK;
  const u16* kTj = kT + (size_t)(b*3+j)*HW*CK;

  s8v qf[4];
  #pragma unroll
  for(int kt=0;kt<4;kt++) qf[kt] = *(const s8v*)(kTi + (size_t)(q0+s)*CK + 32*kt + 8*g);

  {
    f4v ra = *(const f4v*)(rs + (size_t)(12*b+2*jj  )*HW + q0 + 4*g);
    f4v rb = *(const f4v*)(rs + (size_t)(12*b+2*jj+1)*HW + q0 + 4*g);
    if (s == 0){
      #pragma unroll
      for(int r=0;r<4;r++) inv16[w][4*g+r] = 1.0f / (ra[r] + rb[r]);
    }
  }
  __syncthreads();

  float* ao = attn_out + (size_t)plane*HW*HW;

  for(int pt=ph*18; pt<ph*18+18; ++pt){
    int p0 = pt*64;
    {
      const char* kbase = (const char*)kTj + (size_t)p0*256;
      char* lK = (char*)ldsK + w*1024;
      #pragma unroll
      for(int it=0; it<4; ++it){
        unsigned Lo = (unsigned)tid*16u + (unsigned)it*4096u;
        unsigned Gs = Lo ^ (((Lo>>8)&7u)<<4);
        gload16(kbase + Gs, lK + it*4096);
      }
    }
    __syncthreads();

    f4v sa[4] = {};
    #pragma unroll
    for(int kt=0;kt<4;kt++){
      #pragma unroll
      for(int nt=0;nt<4;nt++){
        unsigned row = (unsigned)(16*nt + s);
        unsigned cb  = ((unsigned)(64*kt + 16*g)) ^ ((row&7u)<<4);
        s8v bfr = *(const s8v*)((const char*)ldsK + row*256 + cb);
        sa[nt] = MFMA(qf[kt], bfr, sa[nt]);
      }
    }
    #pragma unroll
    for(int r=0;r<4;r++){
      #pragma unroll
      for(int nt=0;nt<4;nt++)
        ptile[w][4*g+r][16*nt+s] = exp2f(sa[nt][r]*C2E);
    }
    #pragma unroll
    for(int pass=0; pass<4; ++pass){
      int row = 4*pass + g;
      float inv = inv16[w][row];
      f4v val = *(const f4v*)&ptile[w][row][4*s];
      #pragma unroll
      for(int u=0;u<4;u++) val[u] *= inv;
      nt_store4(ao + (size_t)(q0+row)*HW + p0 + 4*s, val);
    }
    __syncthreads();
  }
}

// ---------------- K3: out = ref + WfL*ref + Wcomb*(sum of partial ctx, normalized) + btot ----------------
__global__ __launch_bounds__(256) void k3_out(const float* __restrict__ x,
                                              const u16* __restrict__ Wf, const u16* __restrict__ Wcomb,
                                              const float* __restrict__ btot, const u16* __restrict__ ctxS,
                                              const float* __restrict__ rs,
                                              float* __restrict__ out){
  int f = blockIdx.y, pb = blockIdx.x*64;
  int tid = threadIdx.x;
  int w = tid>>6, l = tid&63, s = l&15, g = l>>4;
  __shared__ char xt[32768];
  const float* xf = x + (size_t)f*CC*HW;
  stage_xt(xf, pb, tid, xt);
  __syncthreads();
  f4v acc[4][4] = {};
  #pragma unroll
  for(int kt=0;kt<8;kt++){              // WfL * ref  (K=256)
    s8v bfr[4];
    #pragma unroll
    for(int nt=0;nt<4;nt++) bfr[nt] = xt_frag(xt, 16*nt+s, kt, g);
    #pragma unroll
    for(int mt=0;mt<4;mt++){
      s8v a = *(const s8v*)(Wf + (size_t)(64*w+16*mt+s)*512 + 32*kt + 8*g);
      #pragma unroll
      for(int nt=0;nt<4;nt++) acc[mt][nt] = MFMA(a, bfr[nt], acc[mt][nt]);
    }
  }
  // Wcomb * (ctxA+ctxB) per jj, then per-column normalize by 1/(rsA+rsB)
  #pragma unroll
  for(int jj=0;jj<2;jj++){
    const u16* cA = ctxS + (size_t)(4*f+2*jj  )*HW*CK;
    const u16* cB = ctxS + (size_t)(4*f+2*jj+1)*HW*CK;
    f4v acc2[4][4] = {};
    #pragma unroll
    for(int kt=0;kt<4;kt++){
      s8v b0[4], b1[4];
      #pragma unroll
      for(int nt=0;nt<4;nt++){
        b0[nt] = *(const s8v*)(cA + (size_t)(pb+16*nt+s)*CK + 32*kt + 8*g);
        b1[nt] = *(const s8v*)(cB + (size_t)(pb+16*nt+s)*CK + 32*kt + 8*g);
      }
      #pragma unroll
      for(int mt=0;mt<4;mt++){
        s8v a = *(const s8v*)(Wcomb + (size_t)(64*w+16*mt+s)*CK + 32*kt + 8*g);
        #pragma unroll
        for(int nt=0;nt<4;nt++){
          acc2[mt][nt] = MFMA(a, b0[nt], acc2[mt][nt]);
          acc2[mt][nt] = MFMA(a, b1[nt], acc2[mt][nt]);
        }
      }
    }
    const float* rA = rs + (size_t)(4*f+2*jj  )*HW;
    const float* rB = rs + (size_t)(4*f+2*jj+1)*HW;
    float invq[4];
    #pragma unroll
    for(int nt=0;nt<4;nt++){
      int q = pb + 16*nt + s;
      invq[nt] = 1.0f / (rA[q] + rB[q]);
    }
    #pragma unroll
    for(int mt=0;mt<4;mt++)
      #pragma unroll
      for(int nt=0;nt<4;nt++)
        #pragma unroll
        for(int r=0;r<4;r++) acc[mt][nt][r] += acc2[mt][nt][r]*invq[nt];
  }
  float* of = out + (size_t)f*CC*HW;
  #pragma unroll
  for(int mt=0;mt<4;mt++){
    #pragma unroll
    for(int r=0;r<4;r++){
      int o = 64*w + 16*mt + 4*g + r;
      float bb = btot[o];
      #pragma unroll
      for(int nt=0;nt<4;nt++){
        int p = pb + 16*nt + s;
        of[(size_t)o*HW + p] = acc[mt][nt][r] + bb + xf[(size_t)o*HW + p];
      }
    }
  }
}

extern "C" void kernel_launch(void* const* d_in, const int* in_sizes, int n_in,
                              void* d_out, int out_size, void* d_ws, size_t ws_size,
                              hipStream_t stream) {
  const float* x     = (const float*)d_in[0];
  const float* Wk    = (const float*)d_in[1];
  const float* bk    = (const float*)d_in[2];
  const float* gk    = (const float*)d_in[3];
  const float* betak = (const float*)d_in[4];
  const float* mk    = (const float*)d_in[5];
  const float* vk    = (const float*)d_in[6];
  const float* Wv    = (const float*)d_in[7];
  const float* bv    = (const float*)d_in[8];
  const float* Wo    = (const float*)d_in[9];
  const float* bo    = (const float*)d_in[10];
  const float* Wf    = (const float*)d_in[11];
  const float* bf    = (const float*)d_in[12];
  float* out = (float*)d_out;

  char* ws = (char*)d_ws;
  u16*   kT     = (u16*)(ws + OFF_KT);
  u16*   vv     = (u16*)(ws + OFF_V);
  u16*   ctxS   = (u16*)(ws + OFF_CTX);    // 48 partial planes of [HW][CK]
  float* rs     = (float*)(ws + OFF_RS);   // 48 x HW partial rowsums
  float* kscale = (float*)(ws + OFF_PAR);
  float* kbias  = kscale + 128;
  float* btot   = kbias + 128;
  u16*   Wk16   = (u16*)(ws + OFF_WK16);
  u16*   Wv16   = (u16*)(ws + OFF_WV16);
  u16*   Wf16   = (u16*)(ws + OFF_WF16);
  u16*   Wcomb  = (u16*)(ws + OFF_WCMB);

  float* attn = out + (size_t)NF*CC*HW;   // 7,077,888 floats in

  k0_params<<<dim3(128), dim3(256), 0, stream>>>(Wk, Wv, bk, gk, betak, mk, vk, Wo, Wf, bo, bf,
                                                 Wk16, Wv16, Wf16, kscale, kbias, btot, Wcomb);
  k1_kv<<<dim3(36,12), dim3(256), 0, stream>>>(x, Wk16, Wv16, bv, kscale, kbias, kT, vv);
  k2_attn<<<dim3(18,48), dim3(256), 0, stream>>>(kT, vv, ctxS, rs);
  k2c_attnmap<<<dim3(36,16), dim3(256), 0, stream>>>(kT, rs, attn);
  k3_out<<<dim3(36,12), dim3(256), 0, stream>>>(x, Wf16, Wcomb, btot, ctxS, rs, out);
}

// Round 19
// 218.472 us; speedup vs baseline: 1.0364x; 1.0364x over previous
//
#include <hip/hip_runtime.h>

typedef short s8v __attribute__((ext_vector_type(8)));   // 8 bf16
typedef short s4v __attribute__((ext_vector_type(4)));   // 4 bf16
typedef float f4v __attribute__((ext_vector_type(4)));
typedef float f16v __attribute__((ext_vector_type(16)));
typedef unsigned u32v2 __attribute__((ext_vector_type(2)));
typedef unsigned u32v4 __attribute__((ext_vector_type(4)));
typedef unsigned short u16;

#define MFMA(a,b,c)   __builtin_amdgcn_mfma_f32_16x16x32_bf16(a,b,c,0,0,0)
#define MFMA32(a,b,c) __builtin_amdgcn_mfma_f32_32x32x16_bf16(a,b,c,0,0,0)

__device__ __forceinline__ float bf2f(u16 x){
  unsigned u = ((unsigned)x) << 16;
  return __builtin_bit_cast(float, u);
}
__device__ __forceinline__ u16 f2bf(float f){
  unsigned u = __builtin_bit_cast(unsigned, f);
  u += 0x7FFFu + ((u >> 16) & 1u);           // RNE
  return (u16)(u >> 16);
}
// packed bf16 convert: D.lo = bf16(lo), D.hi = bf16(hi)
__device__ __forceinline__ unsigned cvtpk(float lo, float hi){
  unsigned r;
  asm("v_cvt_pk_bf16_f32 %0, %1, %2" : "=v"(r) : "v"(lo), "v"(hi));
  return r;
}
// cross-half exchange: lanes<32 receive y from lane+32 (into y), lanes>=32 receive x from lane-32 (into x)
__device__ __forceinline__ void plswap(unsigned &x, unsigned &y){
  asm volatile("v_permlane32_swap_b32 %0, %1" : "+v"(x), "+v"(y));
}

__device__ __forceinline__ void gload16(const void* g, void* l){
  __builtin_amdgcn_global_load_lds((const __attribute__((address_space(1))) unsigned*)g,
                                   (__attribute__((address_space(3))) unsigned*)l, 16, 0, 0);
}
__device__ __forceinline__ void nt_store4(float* p, f4v v){
  __builtin_nontemporal_store(v, (f4v*)p);
}

// ---------------- problem constants ----------------
#define CC   256
#define CK   128
#define HW   2304
#define NF   12          // B*N frames
// exp2 constant: 128^-0.5 * log2(e)
#define C2E  0.1275174996992022f
// ws byte offsets (kT | v | ctx48 | rs48 | params | weights)
#define OFF_KT   0u
#define OFF_V    7077888u
#define OFF_CTX  14155776u
#define OFF_RS   42467328u
#define OFF_PAR  42909696u
#define OFF_WK16 42911744u
#define OFF_WV16 42977280u
#define OFF_WF16 43042816u
#define OFF_WCMB 43304960u

// ---------------- K0: weight converts + params (BN fold, Wcomb = WfR*Wo, btot) ----------------
__global__ void k0_params(const float* __restrict__ Wkf, const float* __restrict__ Wvf,
                          const float* __restrict__ bk, const float* __restrict__ gk,
                          const float* __restrict__ betak, const float* __restrict__ mk,
                          const float* __restrict__ vk, const float* __restrict__ Wo,
                          const float* __restrict__ Wf, const float* __restrict__ bo,
                          const float* __restrict__ bfv,
                          u16* __restrict__ Wk16, u16* __restrict__ Wv16, u16* __restrict__ Wf16,
                          float* kscale, float* kbias, float* btot, u16* Wcomb){
  int c = blockIdx.x;      // 0..127
  int o = threadIdx.x;     // 0..255
  int gid = c*256 + o;     // 0..32767
  Wk16[gid] = f2bf(Wkf[gid]);
  Wv16[gid] = f2bf(Wvf[gid]);
  {
    f4v wf4 = *(const f4v*)(Wf + (size_t)gid*4);
    #pragma unroll
    for(int u=0;u<4;u++) Wf16[(size_t)gid*4+u] = f2bf(wf4[u]);
  }
  float acc = 0.f;
  for(int m=0;m<256;m++)
    acc += Wf[(size_t)o*512 + 256 + m] * Wo[(size_t)m*128 + c];
  Wcomb[(size_t)o*128 + c] = f2bf(acc);
  if (c == 0){
    float a2 = 0.f;
    for(int m=0;m<256;m++)
      a2 += Wf[(size_t)o*512 + 256 + m] * bo[m];
    btot[o] = bfv[o] + 2.0f*a2;
    if (o < 128){
      float inv = gk[o] * rsqrtf(vk[o] + 1e-5f);
      kscale[o] = inv;
      kbias[o]  = betak[o] + (bk[o] - mk[o])*inv;
    }
  }
}

// ---- shared helper: stage x[c][pb+0..63] fp32 -> LDS bf16 tile, rows p (512 B, XOR-swizzled) ----
// c-pair packed: one u32 LDS write covers (c even, c odd) via v_cvt_pk_bf16_f32.
__device__ __forceinline__ void stage_xt(const float* __restrict__ xf, int pb, int tid, char* xt){
  #pragma unroll
  for(int it=0; it<8; ++it){
    int idx = tid + 256*it;          // 0..2047: cp = c/2 (0..127), slot (0..15)
    int cp = idx>>4, slot = idx&15;
    const float* s0 = xf + (size_t)(2*cp  )*HW + pb + slot*4;
    const float* s1 = xf + (size_t)(2*cp+1)*HW + pb + slot*4;
    f4v va = *(const f4v*)s0;
    f4v vb = *(const f4v*)s1;
    #pragma unroll
    for(int u=0;u<4;u++){
      int p = slot*4+u;
      *(unsigned*)(xt + p*512 + ((4*cp) ^ ((p&7)<<4))) = cvtpk(va[u], vb[u]);
    }
  }
}
__device__ __forceinline__ s8v xt_frag(const char* xt, int r, int kt, int g){
  return *(const s8v*)(xt + r*512 + (((unsigned)(64*kt+16*g)) ^ ((unsigned)(r&7)<<4)));
}

// ---------------- K1: kT = BN(x^T*Wk^T) (stored [q][o]), v = Wv*x (stored [o][p]) ----------------
__global__ __launch_bounds__(256) void k1_kv(const float* __restrict__ x, const u16* __restrict__ Wk,
                                             const u16* __restrict__ Wv, const float* __restrict__ bv,
                                             const float* __restrict__ kscale, const float* __restrict__ kbias,
                                             u16* __restrict__ kT, u16* __restrict__ vout){
  int f  = blockIdx.y;
  int pb = blockIdx.x*64;
  int tid = threadIdx.x;
  int w = tid>>6, l = tid&63, s = l&15, g = l>>4;
  __shared__ char xt[32768];
  stage_xt(x + (size_t)f*CC*HW, pb, tid, xt);
  __syncthreads();
  { // k path
    s8v afr[8];
    #pragma unroll
    for(int kt=0;kt<8;kt++) afr[kt] = xt_frag(xt, 16*w+s, kt, g);
    f4v acc[8] = {};
    #pragma unroll
    for(int kt=0;kt<8;kt++){
      #pragma unroll
      for(int nt=0;nt<8;nt++){
        s8v b = *(const s8v*)(Wk + (size_t)(16*nt+s)*CC + 32*kt + 8*g);
        acc[nt] = MFMA(afr[kt], b, acc[nt]);
      }
    }
    u16* kout = kT + (size_t)f*HW*CK;
    int q0 = pb + 16*w;
    #pragma unroll
    for(int nt=0;nt<8;nt++){
      int o = 16*nt + s;
      float sc = kscale[o], bi = kbias[o];
      #pragma unroll
      for(int r=0;r<4;r++){
        int q = q0 + 4*g + r;
        kout[(size_t)q*CK + o] = f2bf(acc[nt][r]*sc + bi);
      }
    }
  }
  { // v path
    s8v afr[2][8];
    #pragma unroll
    for(int mt=0;mt<2;mt++)
      #pragma unroll
      for(int kt=0;kt<8;kt++)
        afr[mt][kt] = *(const s8v*)(Wv + (size_t)(32*w+16*mt+s)*CC + 32*kt + 8*g);
    f4v acc[2][4] = {};
    #pragma unroll
    for(int kt=0;kt<8;kt++){
      #pragma unroll
      for(int nt=0;nt<4;nt++){
        s8v b = xt_frag(xt, 16*nt+s, kt, g);
        #pragma unroll
        for(int mt=0;mt<2;mt++)
          acc[mt][nt] = MFMA(afr[mt][kt], b, acc[mt][nt]);
      }
    }
    u16* vf = vout + (size_t)f*CK*HW;
    #pragma unroll
    for(int mt=0;mt<2;mt++){
      #pragma unroll
      for(int r=0;r<4;r++){
        int o = 32*w + 16*mt + 4*g + r;
        float bvo = bv[o];
        #pragma unroll
        for(int nt=0;nt<4;nt++)
          vf[(size_t)o*HW + pb + 16*nt + s] = f2bf(acc[mt][nt][r] + bvo);
      }
    }
  }
}

// ---------------- K2: attention core, 32x32 MFMA + in-register P (no P LDS round-trip).
//  p-split x2; 128 q x 64 p tiles; K+V LDS dbuf (64 KB); swapped QK^T: D[p][q], q = lane&31.
//  Writes UNNORMALIZED partial ctx (48 planes) + partial rowsums; k2c/k3 combine. ----------------
__global__ __launch_bounds__(256, 2) void k2_attn(const u16* __restrict__ kT, const u16* __restrict__ v,
                                                  u16* __restrict__ ctxS, float* __restrict__ rs){
  int qb  = blockIdx.x;          // 0..17 (128 q rows each)
  int yy  = blockIdx.y;          // 0..47 = bij*2 + half
  int bij = yy>>1, half = yy&1;
  int b = bij/6, r6_ = bij - 6*b, i = r6_>>1, jj = r6_&1;
  int adj0 = (i==0) ? 1 : 0;
  int adj1 = (i==2) ? 1 : 2;
  int j = jj ? adj1 : adj0;
  int tid = threadIdx.x;
  int w = tid>>6, l = tid&63;
  int lq = l&31, hh = l>>5;      // q-col within wave block, half
  int q0 = qb*128 + w*32;        // wave covers q0..q0+31

  __shared__ char L[65536];      // K dbuf 2x16K | V dbuf 2x16K

  const u16* kTi = kT + (size_t)(b*3+i)*HW*CK;
  const u16* kTj = kT + (size_t)(b*3+j)*HW*CK;
  const u16* vj  = v  + (size_t)(b*3+j)*CK*HW;

  // Q B-frags: col=q=lq, k = c = 16*st + 8*hh + jv
  s8v qfr[8];
  #pragma unroll
  for(int st=0; st<8; ++st)
    qfr[st] = *(const s8v*)(kTi + (size_t)(q0+lq)*CK + 16*st + 8*hh);

  f16v ctx[4] = {};              // 4 c-blocks, D[c][q]
  float psum = 0.f;

  // ---- staging: K tile (64x256B rows) + V tile (128x128B rows), XOR-swizzled source ----
  auto STAGE = [&](int p0, int buf){
    const char* kbase = (const char*)kTj + (size_t)p0*256;
    const char* vbase = (const char*)vj  + (size_t)p0*2;
    char* lK = L + buf*16384 + w*1024;
    char* lV = L + 32768 + buf*16384 + w*1024;
    #pragma unroll
    for(int it=0; it<4; ++it){
      unsigned Lo = (unsigned)tid*16u + (unsigned)it*4096u;
      unsigned Gs = Lo ^ (((Lo>>8)&7u)<<4);               // K: 256 B rows
      gload16(kbase + Gs, lK + it*4096);
      unsigned row = Lo>>7;                               // V: 128 B rows
      unsigned col = (Lo & 127u) ^ ((row&7u)<<4);
      gload16(vbase + (size_t)row*(HW*2) + col, lV + it*4096);
    }
  };

  int pbase = half*18;
  STAGE(pbase*64, 0);
  __syncthreads();
  int cur = 0;

  for(int pt=0; pt<18; ++pt){
    int p0 = (pbase + pt)*64;
    if (pt < 17) STAGE(p0+64, cur^1);         // issue next-tile DMA before compute
    const char* lK = L + cur*16384;
    const char* lV = L + 32768 + cur*16384;

    // ---- QK^T swapped 32x32: sa[pb] = S^T tile, row=p (16/lane), col=q=lq ----
    f16v sa[2] = {};
    #pragma unroll
    for(int st=0; st<8; ++st){
      #pragma unroll
      for(int pb=0; pb<2; ++pb){
        unsigned row = (unsigned)(32*pb + lq);
        unsigned cb_ = ((unsigned)(32*st + 16*hh)) ^ ((row&7u)<<4);
        s8v kfr = *(const s8v*)(lK + row*256 + cb_);
        sa[pb] = MFMA32(kfr, qfr[st], sa[pb]);
      }
    }
    // ---- per-pb: exp2 + rowsum + cvt_pk + permlane exchange -> 2 P-frags, then PV ----
    #pragma unroll
    for(int pb=0; pb<2; ++pb){
      float e0 = exp2f(sa[pb][0]*C2E),  e1 = exp2f(sa[pb][1]*C2E);
      float e2 = exp2f(sa[pb][2]*C2E),  e3 = exp2f(sa[pb][3]*C2E);
      float e4 = exp2f(sa[pb][4]*C2E),  e5 = exp2f(sa[pb][5]*C2E);
      float e6 = exp2f(sa[pb][6]*C2E),  e7 = exp2f(sa[pb][7]*C2E);
      float e8 = exp2f(sa[pb][8]*C2E),  e9 = exp2f(sa[pb][9]*C2E);
      float ea = exp2f(sa[pb][10]*C2E), eb = exp2f(sa[pb][11]*C2E);
      float ec = exp2f(sa[pb][12]*C2E), ed = exp2f(sa[pb][13]*C2E);
      float ee = exp2f(sa[pb][14]*C2E), ef = exp2f(sa[pb][15]*C2E);
      psum += ((e0+e1)+(e2+e3)) + ((e4+e5)+(e6+e7)) +
              ((e8+e9)+(ea+eb)) + ((ec+ed)+(ee+ef));
      unsigned c0 = cvtpk(e0,e1), c1 = cvtpk(e2,e3), c2 = cvtpk(e4,e5), c3 = cvtpk(e6,e7);
      unsigned c4 = cvtpk(e8,e9), c5 = cvtpk(ea,eb), c6 = cvtpk(ec,ed), c7 = cvtpk(ee,ef);
      plswap(c0, c2); plswap(c1, c3);       // octet p' 0..15
      plswap(c4, c6); plswap(c5, c7);       // octet p' 16..31
      u32v4 w0 = {c0, c1, c2, c3};
      u32v4 w1 = {c4, c5, c6, c7};
      s8v pf0 = __builtin_bit_cast(s8v, w0);  // P frag, K-step p = 32*pb + 0..15
      s8v pf1 = __builtin_bit_cast(s8v, w1);  // P frag, K-step p = 32*pb + 16..31
      #pragma unroll
      for(int cb=0; cb<4; ++cb){
        unsigned row = (unsigned)(32*cb + lq);
        unsigned swz = (row&7u)<<4;
        unsigned off0 = ((unsigned)(64*pb      + 16*hh)) ^ swz;
        unsigned off1 = ((unsigned)(64*pb + 32 + 16*hh)) ^ swz;
        s8v vf0 = *(const s8v*)(lV + row*128 + off0);
        s8v vf1 = *(const s8v*)(lV + row*128 + off1);
        ctx[cb] = MFMA32(vf0, pf0, ctx[cb]);
        ctx[cb] = MFMA32(vf1, pf1, ctx[cb]);
      }
    }
    __syncthreads();   // next tiles landed + all waves done with cur
    cur ^= 1;
  }

  // ---- rowsum: lane pair (lq, lq+32) both hold partial sums for q = q0+lq ----
  float xsum = psum + __shfl_xor(psum, 32);
  if (l < 32)
    rs[(size_t)yy*HW + q0 + lq] = xsum;

  // ---- write UNNORMALIZED partial ctx plane [yy][q][c]; c = 32cb + 8qd + 4hh + 0..3 ----
  u16* cS = ctxS + (size_t)yy*HW*CK;
  #pragma unroll
  for(int cb=0; cb<4; ++cb){
    #pragma unroll
    for(int qd=0; qd<4; ++qd){
      u32v2 pk;
      pk[0] = cvtpk(ctx[cb][4*qd+0], ctx[cb][4*qd+1]);
      pk[1] = cvtpk(ctx[cb][4*qd+2], ctx[cb][4*qd+3]);
      *(u32v2*)(cS + (size_t)(q0+lq)*CK + 32*cb + 8*qd + 4*hh) = pk;
    }
  }
}

// ---------------- K2c: recompute QK^T for i==0 planes, write NORMALIZED fp32 attn (NT stores) ----------------
__global__ __launch_bounds__(256) void k2c_attnmap(const u16* __restrict__ kT,
                                                   const float* __restrict__ rs,
                                                   float* __restrict__ attn_out){
  int qb = blockIdx.x;           // 0..35
  int y  = blockIdx.y;           // 0..15: plane = y>>1, ph = y&1
  int plane = y>>1, ph = y&1;
  int b = plane>>1, jj = plane&1, j = jj + 1;   // i==0: adj frames are 1,2
  int tid = threadIdx.x;
  int w = tid>>6, l = tid&63, s = l&15, g = l>>4;
  int q0 = qb*64 + w*16;

  __shared__ char  ldsK[16384];
  __shared__ float ptile[4][16][68];
  __shared__ float inv16[4][16];

  const u16* kTi = kT + (size_t)(b*3)*HW*CK;
  const u16* kTj = kT + (size_t)(b*3+j)*HW*CK;

  s8v qf[4];
  #pragma unroll
  for(int kt=0;kt<4;kt++) qf[kt] = *(const s8v*)(kTi + (size_t)(q0+s)*CK + 32*kt + 8*g);

  {
    f4v ra = *(const f4v*)(rs + (size_t)(12*b+2*jj  )*HW + q0 + 4*g);
    f4v rb = *(const f4v*)(rs + (size_t)(12*b+2*jj+1)*HW + q0 + 4*g);
    if (s == 0){
      #pragma unroll
      for(int r=0;r<4;r++) inv16[w][4*g+r] = 1.0f / (ra[r] + rb[r]);
    }
  }
  __syncthreads();

  float* ao = attn_out + (size_t)plane*HW*HW;

  for(int pt=ph*18; pt<ph*18+18; ++pt){
    int p0 = pt*64;
    {
      const char* kbase = (const char*)kTj + (size_t)p0*256;
      char* lK = (char*)ldsK + w*1024;
      #pragma unroll
      for(int it=0; it<4; ++it){
        unsigned Lo = (unsigned)tid*16u + (unsigned)it*4096u;
        unsigned Gs = Lo ^ (((Lo>>8)&7u)<<4);
        gload16(kbase + Gs, lK + it*4096);
      }
    }
    __syncthreads();

    f4v sa[4] = {};
    #pragma unroll
    for(int kt=0;kt<4;kt++){
      #pragma unroll
      for(int nt=0;nt<4;nt++){
        unsigned row = (unsigned)(16*nt + s);
        unsigned cb  = ((unsigned)(64*kt + 16*g)) ^ ((row&7u)<<4);
        s8v bfr = *(const s8v*)((const char*)ldsK + row*256 + cb);
        sa[nt] = MFMA(qf[kt], bfr, sa[nt]);
      }
    }
    #pragma unroll
    for(int r=0;r<4;r++){
      #pragma unroll
      for(int nt=0;nt<4;nt++)
        ptile[w][4*g+r][16*nt+s] = exp2f(sa[nt][r]*C2E);
    }
    #pragma unroll
    for(int pass=0; pass<4; ++pass){
      int row = 4*pass + g;
      float inv = inv16[w][row];
      f4v val = *(const f4v*)&ptile[w][row][4*s];
      #pragma unroll
      for(int u=0;u<4;u++) val[u] *= inv;
      nt_store4(ao + (size_t)(q0+row)*HW + p0 + 4*s, val);
    }
    __syncthreads();
  }
}

// ---------------- K3: out = ref + WfL*ref + Wcomb*(sum of partial ctx, normalized) + btot ----------------
__global__ __launch_bounds__(256) void k3_out(const float* __restrict__ x,
                                              const u16* __restrict__ Wf, const u16* __restrict__ Wcomb,
                                              const float* __restrict__ btot, const u16* __restrict__ ctxS,
                                              const float* __restrict__ rs,
                                              float* __restrict__ out){
  int f = blockIdx.y, pb = blockIdx.x*64;
  int tid = threadIdx.x;
  int w = tid>>6, l = tid&63, s = l&15, g = l>>4;
  __shared__ char xt[32768];
  const float* xf = x + (size_t)f*CC*HW;
  stage_xt(xf, pb, tid, xt);
  __syncthreads();
  f4v acc[4][4] = {};
  #pragma unroll
  for(int kt=0;kt<8;kt++){              // WfL * ref  (K=256)
    s8v bfr[4];
    #pragma unroll
    for(int nt=0;nt<4;nt++) bfr[nt] = xt_frag(xt, 16*nt+s, kt, g);
    #pragma unroll
    for(int mt=0;mt<4;mt++){
      s8v a = *(const s8v*)(Wf + (size_t)(64*w+16*mt+s)*512 + 32*kt + 8*g);
      #pragma unroll
      for(int nt=0;nt<4;nt++) acc[mt][nt] = MFMA(a, bfr[nt], acc[mt][nt]);
    }
  }
  // Wcomb * (ctxA+ctxB) per jj, then per-column normalize by 1/(rsA+rsB)
  #pragma unroll
  for(int jj=0;jj<2;jj++){
    const u16* cA = ctxS + (size_t)(4*f+2*jj  )*HW*CK;
    const u16* cB = ctxS + (size_t)(4*f+2*jj+1)*HW*CK;
    f4v acc2[4][4] = {};
    #pragma unroll
    for(int kt=0;kt<4;kt++){
      s8v b0[4], b1[4];
      #pragma unroll
      for(int nt=0;nt<4;nt++){
        b0[nt] = *(const s8v*)(cA + (size_t)(pb+16*nt+s)*CK + 32*kt + 8*g);
        b1[nt] = *(const s8v*)(cB + (size_t)(pb+16*nt+s)*CK + 32*kt + 8*g);
      }
      #pragma unroll
      for(int mt=0;mt<4;mt++){
        s8v a = *(const s8v*)(Wcomb + (size_t)(64*w+16*mt+s)*CK + 32*kt + 8*g);
        #pragma unroll
        for(int nt=0;nt<4;nt++){
          acc2[mt][nt] = MFMA(a, b0[nt], acc2[mt][nt]);
          acc2[mt][nt] = MFMA(a, b1[nt], acc2[mt][nt]);
        }
      }
    }
    const float* rA = rs + (size_t)(4*f+2*jj  )*HW;
    const float* rB = rs + (size_t)(4*f+2*jj+1)*HW;
    float invq[4];
    #pragma unroll
    for(int nt=0;nt<4;nt++){
      int q = pb + 16*nt + s;
      invq[nt] = 1.0f / (rA[q] + rB[q]);
    }
    #pragma unroll
    for(int mt=0;mt<4;mt++)
      #pragma unroll
      for(int nt=0;nt<4;nt++)
        #pragma unroll
        for(int r=0;r<4;r++) acc[mt][nt][r] += acc2[mt][nt][r]*invq[nt];
  }
  float* of = out + (size_t)f*CC*HW;
  #pragma unroll
  for(int mt=0;mt<4;mt++){
    #pragma unroll
    for(int r=0;r<4;r++){
      int o = 64*w + 16*mt + 4*g + r;
      float bb = btot[o];
      #pragma unroll
      for(int nt=0;nt<4;nt++){
        int p = pb + 16*nt + s;
        of[(size_t)o*HW + p] = acc[mt][nt][r] + bb + xf[(size_t)o*HW + p];
      }
    }
  }
}

extern "C" void kernel_launch(void* const* d_in, const int* in_sizes, int n_in,
                              void* d_out, int out_size, void* d_ws, size_t ws_size,
                              hipStream_t stream) {
  const float* x     = (const float*)d_in[0];
  const float* Wk    = (const float*)d_in[1];
  const float* bk    = (const float*)d_in[2];
  const float* gk    = (const float*)d_in[3];
  const float* betak = (const float*)d_in[4];
  const float* mk    = (const float*)d_in[5];
  const float* vk    = (const float*)d_in[6];
  const float* Wv    = (const float*)d_in[7];
  const float* bv    = (const float*)d_in[8];
  const float* Wo    = (const float*)d_in[9];
  const float* bo    = (const float*)d_in[10];
  const float* Wf    = (const float*)d_in[11];
  const float* bf    = (const float*)d_in[12];
  float* out = (float*)d_out;

  char* ws = (char*)d_ws;
  u16*   kT     = (u16*)(ws + OFF_KT);
  u16*   vv     = (u16*)(ws + OFF_V);
  u16*   ctxS   = (u16*)(ws + OFF_CTX);    // 48 partial planes of [HW][CK]
  float* rs     = (float*)(ws + OFF_RS);   // 48 x HW partial rowsums
  float* kscale = (float*)(ws + OFF_PAR);
  float* kbias  = kscale + 128;
  float* btot   = kbias + 128;
  u16*   Wk16   = (u16*)(ws + OFF_WK16);
  u16*   Wv16   = (u16*)(ws + OFF_WV16);
  u16*   Wf16   = (u16*)(ws + OFF_WF16);
  u16*   Wcomb  = (u16*)(ws + OFF_WCMB);

  float* attn = out + (size_t)NF*CC*HW;   // 7,077,888 floats in

  k0_params<<<dim3(128), dim3(256), 0, stream>>>(Wk, Wv, bk, gk, betak, mk, vk, Wo, Wf, bo, bf,
                                                 Wk16, Wv16, Wf16, kscale, kbias, btot, Wcomb);
  k1_kv<<<dim3(36,12), dim3(256), 0, stream>>>(x, Wk16, Wv16, bv, kscale, kbias, kT, vv);
  k2_attn<<<dim3(18,48), dim3(256), 0, stream>>>(kT, vv, ctxS, rs);
  k2c_attnmap<<<dim3(36,16), dim3(256), 0, stream>>>(kT, rs, attn);
  k3_out<<<dim3(36,12), dim3(256), 0, stream>>>(x, Wf16, Wcomb, btot, ctxS, rs, out);
}